// Round 1
// baseline (451.544 us; speedup 1.0000x reference)
//
#include <hip/hip_runtime.h>
#include <stdint.h>

typedef short   shortx8 __attribute__((ext_vector_type(8)));
typedef float   f32x4   __attribute__((ext_vector_type(4)));

static __device__ __forceinline__ unsigned short f2bf(float f) {
  unsigned u = __float_as_uint(f);
  unsigned r = u + 0x7FFFu + ((u >> 16) & 1u);   // RTNE
  return (unsigned short)(r >> 16);
}

// ---------------- K0: wmax = max(relu(w)) ----------------
__global__ void k_wmax(const float* __restrict__ w, int n, unsigned* __restrict__ wmax_u) {
  int i = blockIdx.x * 256 + threadIdx.x;
  float v = 0.f;
  if (i < n) v = fmaxf(w[i], 0.f);
  for (int m = 32; m; m >>= 1) v = fmaxf(v, __shfl_xor(v, m));
  if ((threadIdx.x & 63) == 0) atomicMax(wmax_u, __float_as_uint(v));
}

// ---------------- K1a: X -> bf16 (zero-padded rows) ----------------
__global__ void k_convx(const float* __restrict__ X, unsigned short* __restrict__ xb,
                        long total, long nelem) {
  long e = (long)(blockIdx.x * 256 + threadIdx.x) * 4;
  if (e >= total) return;
  ushort4 us;
  if (e < nelem) {
    float4 v = *(const float4*)(X + e);
    us.x = f2bf(v.x); us.y = f2bf(v.y); us.z = f2bf(v.z); us.w = f2bf(v.w);
  } else { us.x = us.y = us.z = us.w = 0; }
  *(ushort4*)(xb + e) = us;
}

// ---------------- K1b: aug[n] = ||x_n||^2 + wmax - w[n] ----------------
__global__ void k_aug(const float* __restrict__ X, const float* __restrict__ w,
                      const unsigned* __restrict__ wmax_u, float* __restrict__ aug,
                      int n, int npad) {
  int r = blockIdx.x * 4 + (threadIdx.x >> 6);
  int lane = threadIdx.x & 63;
  if (r >= npad) return;
  if (r < n) {
    float a = X[(size_t)r * 128 + lane];
    float b = X[(size_t)r * 128 + 64 + lane];
    float s = a * a + b * b;
    for (int m = 32; m; m >>= 1) s += __shfl_xor(s, m);
    if (lane == 0) aug[r] = s + __uint_as_float(*wmax_u) - w[r];
  } else {
    if (lane == 0) aug[r] = 1e30f;   // pad rows can never be candidates
  }
}

// ---------------- K1c: queries -> bf16, q2 = ||q||^2 ----------------
__global__ void k_q(const float* __restrict__ xt, unsigned short* __restrict__ qb,
                    float* __restrict__ q2, int B) {
  int r = blockIdx.x * 4 + (threadIdx.x >> 6);
  int lane = threadIdx.x & 63;
  if (r >= B) return;
  float a = xt[(size_t)r * 128 + lane];
  float b = xt[(size_t)r * 128 + 64 + lane];
  qb[(size_t)r * 128 + lane] = f2bf(a);
  qb[(size_t)r * 128 + 64 + lane] = f2bf(b);
  float s = a * a + b * b;
  for (int m = 32; m; m >>= 1) s += __shfl_xor(s, m);
  if (lane == 0) q2[r] = s;
}

// ---------------- K2: bf16 MFMA GEMM -> per-(query,chunk64) min of s ----------------
// s[q,n] = aug[n] - 2*q.x  (q2 omitted: constant per row, doesn't affect ranking)
__global__ __launch_bounds__(256) void k_gemm(const unsigned short* __restrict__ qb,
    const unsigned short* __restrict__ xb, const float* __restrict__ aug,
    float* __restrict__ cmin, int C, int cps) {
  __shared__ __align__(16) unsigned short tile[64 * 128];
  const int t = threadIdx.x;
  const int lane = t & 63, wv = t >> 6;
  const int li = lane & 15, lg = lane >> 4;
  const int qbase = blockIdx.x * 128 + wv * 32;

  // A fragments: 32 queries x 128 k, resident in registers for the whole stripe
  shortx8 af[2][4];
#pragma unroll
  for (int tt = 0; tt < 2; ++tt)
#pragma unroll
    for (int ks = 0; ks < 4; ++ks)
      af[tt][ks] = *(const shortx8*)(qb + (size_t)(qbase + tt * 16 + li) * 128 + ks * 32 + lg * 8);

  const int c0 = blockIdx.y * cps;
  const int c1 = min(c0 + cps, C);
  for (int c = c0; c < c1; ++c) {
    __syncthreads();
    { // stage 64x128 bf16 chunk, XOR-swizzled (G4: byte ^= (row&7)<<4)
      const unsigned short* src = xb + (size_t)c * 8192;
#pragma unroll
      for (int p = 0; p < 4; ++p) {
        int e = p * 2048 + t * 8;
        shortx8 v = *(const shortx8*)(src + e);
        int r = e >> 7, cc = e & 127;
        *(shortx8*)(tile + r * 128 + (cc ^ ((r & 7) << 3))) = v;
      }
    }
    __syncthreads();

    f32x4 acc[2][4];
#pragma unroll
    for (int tt = 0; tt < 2; ++tt)
#pragma unroll
      for (int cg = 0; cg < 4; ++cg)
        acc[tt][cg] = (f32x4){0.f, 0.f, 0.f, 0.f};

#pragma unroll
    for (int cg = 0; cg < 4; ++cg) {
      const int r = cg * 16 + li;
      const int rsw = (r & 7) << 3;
      shortx8 bf[4];
#pragma unroll
      for (int ks = 0; ks < 4; ++ks)
        bf[ks] = *(const shortx8*)(tile + r * 128 + ((ks * 32 + lg * 8) ^ rsw));
#pragma unroll
      for (int tt = 0; tt < 2; ++tt)
#pragma unroll
        for (int ks = 0; ks < 4; ++ks)
          acc[tt][cg] = __builtin_amdgcn_mfma_f32_16x16x32_bf16(af[tt][ks], bf[ks], acc[tt][cg], 0, 0, 0);
    }

    float aaug[4];
#pragma unroll
    for (int cg = 0; cg < 4; ++cg) aaug[cg] = aug[c * 64 + cg * 16 + li];

    // per-lane min over 4 col-groups, then across the 16-lane group (= min over 64 cols)
    float mm[2][4];
#pragma unroll
    for (int tt = 0; tt < 2; ++tt)
#pragma unroll
      for (int p = 0; p < 4; ++p) {
        float v = aaug[0] - 2.f * acc[tt][0][p];
#pragma unroll
        for (int cg = 1; cg < 4; ++cg) v = fminf(v, aaug[cg] - 2.f * acc[tt][cg][p]);
        mm[tt][p] = v;
      }
#pragma unroll
    for (int msk = 1; msk < 16; msk <<= 1) {
#pragma unroll
      for (int tt = 0; tt < 2; ++tt)
#pragma unroll
        for (int p = 0; p < 4; ++p)
          mm[tt][p] = fminf(mm[tt][p], __shfl_xor(mm[tt][p], msk));
    }
    if (li < 8) {   // C/D layout: col=lane&15, row=(lane>>4)*4+reg  [m89/m91]
      const int tt = li >> 2, p = li & 3;
      float v;
      if (tt == 0) v = (p == 0) ? mm[0][0] : (p == 1) ? mm[0][1] : (p == 2) ? mm[0][2] : mm[0][3];
      else         v = (p == 0) ? mm[1][0] : (p == 1) ? mm[1][1] : (p == 2) ? mm[1][2] : mm[1][3];
      cmin[(size_t)(qbase + tt * 16 + lg * 4 + p) * C + c] = v;
    }
  }
}

// ---------------- K3a: tau[q] = (2k-th smallest chunk-min) + 1.0 ----------------
__global__ void k_tau(const float* __restrict__ cmin, float* __restrict__ tau,
                      const int* __restrict__ kptr, int C) {
  __shared__ float arr[1600];
  __shared__ float lastv_s;
  const int q = blockIdx.x, t = threadIdx.x;
  for (int i = t; i < C; i += 64) arr[i] = cmin[(size_t)q * C + i];
  __syncthreads();
  int m = 2 * (*kptr);
  if (m < 16) m = 16; if (m > 64) m = 64; if (m > C) m = C;
  for (int r = 0; r < m; ++r) {
    float md = 1e38f; int mi = 0x7fffffff;
    for (int i = t; i < C; i += 64)
      if (arr[i] < md || (arr[i] == md && i < mi)) { md = arr[i]; mi = i; }
    for (int msk = 32; msk; msk >>= 1) {
      float od = __shfl_xor(md, msk); int oi = __shfl_xor(mi, msk);
      if (od < md || (od == md && oi < mi)) { md = od; mi = oi; }
    }
    if (t == 0) { if (mi < C) arr[mi] = 1e38f; lastv_s = md; }
    __syncthreads();
  }
  if (t == 0) tau[q] = lastv_s + 1.0f;
}

// ---------------- K3b: invert to per-chunk query lists ----------------
__global__ void k_pairs(const float* __restrict__ cmin, const float* __restrict__ tau,
                        int* __restrict__ ccnt, int* __restrict__ clist, int C, int B) {
  int c = blockIdx.x * 256 + threadIdx.x;
  int q = blockIdx.y;
  if (c >= C) return;
  if (cmin[(size_t)q * C + c] <= tau[q]) {
    int pos = atomicAdd(&ccnt[c], 1);
    clist[(size_t)c * B + pos] = q;
  }
}

// ---------------- K4: exact fp32 recompute for selected (query, chunk) pairs ----------------
__global__ __launch_bounds__(256) void k_exact(const float* __restrict__ X, const float* __restrict__ xt,
    const float* __restrict__ aug, const float* __restrict__ q2, const float* __restrict__ tau,
    const int* __restrict__ ccnt, const int* __restrict__ clist,
    int* __restrict__ qcnt, float2* __restrict__ cand, int n, int B) {
  __shared__ float xs[64 * 129];
  __shared__ float qs[4][128];
  const int c = blockIdx.x;
  const int t = threadIdx.x;
  for (int i = t; i < 8192; i += 256) {
    int r = i >> 7, cc = i & 127;
    long g = (long)c * 64 + r;
    xs[r * 129 + cc] = (g < n) ? X[g * 128 + cc] : 0.f;
  }
  __syncthreads();
  const int nq = ccnt[c];
  if (nq == 0) return;
  const int wv = t >> 6, lane = t & 63;
  const int gcol = c * 64 + lane;
  const float augv = aug[gcol];
  for (int i = wv; i < nq; i += 4) {
    const int q = clist[(size_t)c * B + i];
    qs[wv][lane] = xt[(size_t)q * 128 + lane];
    qs[wv][64 + lane] = xt[(size_t)q * 128 + 64 + lane];
    __asm__ volatile("s_waitcnt lgkmcnt(0)" ::: "memory");
    float acc = 0.f;
#pragma unroll 8
    for (int kk = 0; kk < 128; ++kk)
      acc = fmaf(qs[wv][kk], xs[lane * 129 + kk], acc);
    const float s = fmaf(-2.f, acc, augv);
    if (gcol < n && s <= tau[q]) {
      int pos = atomicAdd(&qcnt[q], 1);
      if (pos < 256) {
        float d2 = (q2[q] - 2.f * acc) + augv;
        cand[(size_t)q * 256 + pos] = make_float2(d2, __int_as_float(gcol));
      }
    }
  }
}

// ---------------- K5: exact top-k (ascending (d2,idx)) + argmax f ----------------
__global__ void k_final(const float* __restrict__ w, const unsigned* __restrict__ wmax_u,
    const float2* __restrict__ cand, const int* __restrict__ qcnt, const int* __restrict__ kptr,
    float* __restrict__ dout, int B, int n) {
  const int q = blockIdx.x, lane = threadIdx.x;
  int k = *kptr; if (k < 1) k = 1; if (k > 64) k = 64;
  const float wmax = __uint_as_float(*wmax_u);
  const int cnt = min(qcnt[q], 256);
  float d0 = 1e38f, d1 = 1e38f, d2v = 1e38f, d3 = 1e38f;
  int i0 = 0x7fffffff, i1 = 0x7fffffff, i2 = 0x7fffffff, i3 = 0x7fffffff;
  {
    int s;
    s = lane;       if (s < cnt) { float2 cc = cand[(size_t)q * 256 + s]; d0 = cc.x; i0 = __float_as_int(cc.y); }
    s = lane + 64;  if (s < cnt) { float2 cc = cand[(size_t)q * 256 + s]; d1 = cc.x; i1 = __float_as_int(cc.y); }
    s = lane + 128; if (s < cnt) { float2 cc = cand[(size_t)q * 256 + s]; d2v = cc.x; i2 = __float_as_int(cc.y); }
    s = lane + 192; if (s < cnt) { float2 cc = cand[(size_t)q * 256 + s]; d3 = cc.x; i3 = __float_as_int(cc.y); }
  }
  float bestf = -1e38f; int besti = 0;
  for (int r = 0; r < k; ++r) {
    float md = d0; int mi = i0; int mj = 0;
    if (d1 < md || (d1 == md && i1 < mi)) { md = d1; mi = i1; mj = 1; }
    if (d2v < md || (d2v == md && i2 < mi)) { md = d2v; mi = i2; mj = 2; }
    if (d3 < md || (d3 == md && i3 < mi)) { md = d3; mi = i3; mj = 3; }
    int ml = lane;
    for (int msk = 32; msk; msk >>= 1) {
      float od = __shfl_xor(md, msk); int oi = __shfl_xor(mi, msk);
      int ol = __shfl_xor(ml, msk);   int oj = __shfl_xor(mj, msk);
      if (od < md || (od == md && oi < mi)) { md = od; mi = oi; ml = ol; mj = oj; }
    }
    if (lane == ml) {   // remove winner (static indices only)
      if (mj == 0)      { d0 = 1e38f;  i0 = 0x7fffffff; }
      else if (mj == 1) { d1 = 1e38f;  i1 = 0x7fffffff; }
      else if (mj == 2) { d2v = 1e38f; i2 = 0x7fffffff; }
      else              { d3 = 1e38f;  i3 = 0x7fffffff; }
    }
    if (mi >= 0 && mi < n) {
      float wi = w[mi];
      float da = sqrtf(fmaxf(md - (wmax - wi), 0.f));
      float f = wi - da;
      if (f > bestf) { bestf = f; besti = mi; }
    }
  }
  if (lane == 0) { dout[q] = bestf; dout[B + q] = (float)besti; }
}

extern "C" void kernel_launch(void* const* d_in, const int* in_sizes, int n_in,
                              void* d_out, int out_size, void* d_ws, size_t ws_size,
                              hipStream_t stream) {
  const float* xt = (const float*)d_in[0];
  const float* X  = (const float*)d_in[1];
  const float* w  = (const float*)d_in[2];
  const int* kptr = (const int*)d_in[3];
  const int B = in_sizes[0] / 128;        // 2048
  const int n = in_sizes[2];              // 100000
  const int C = (n + 63) / 64;            // 1563 chunks of 64
  const int npad = C * 64;

  char* ws = (char*)d_ws;
  const size_t o_wmax = 0, o_ccnt = 1024, o_qcnt = 8192;
  const size_t o_q2   = 16384;
  const size_t o_tau  = o_q2 + (size_t)B * 4;
  const size_t o_aug  = o_tau + (size_t)B * 4;
  const size_t o_cmin = (o_aug + (size_t)npad * 4 + 255) & ~(size_t)255;
  const size_t o_clist= (o_cmin + (size_t)B * C * 4 + 255) & ~(size_t)255;
  const size_t o_cand = (o_clist + (size_t)C * B * 4 + 255) & ~(size_t)255;
  const size_t o_qb   = (o_cand + (size_t)B * 256 * 8 + 255) & ~(size_t)255;
  const size_t o_xb   = (o_qb + (size_t)B * 128 * 2 + 255) & ~(size_t)255;

  unsigned* wmax_u = (unsigned*)(ws + o_wmax);
  int* ccnt  = (int*)(ws + o_ccnt);
  int* qcnt  = (int*)(ws + o_qcnt);
  float* q2  = (float*)(ws + o_q2);
  float* tau = (float*)(ws + o_tau);
  float* aug = (float*)(ws + o_aug);
  float* cmin = (float*)(ws + o_cmin);
  int* clist = (int*)(ws + o_clist);
  float2* cand = (float2*)(ws + o_cand);
  unsigned short* qb = (unsigned short*)(ws + o_qb);
  unsigned short* xb = (unsigned short*)(ws + o_xb);

  hipMemsetAsync(d_ws, 0, 16384, stream);  // wmax + chunk counts + query counts

  k_wmax<<<(n + 255) / 256, 256, 0, stream>>>(w, n, wmax_u);
  const long total = (long)npad * 128;
  k_convx<<<(int)((total / 4 + 255) / 256), 256, 0, stream>>>(X, xb, total, (long)n * 128);
  k_aug<<<(npad + 3) / 4, 256, 0, stream>>>(X, w, wmax_u, aug, n, npad);
  k_q<<<(B + 3) / 4, 256, 0, stream>>>(xt, qb, q2, B);

  const int cps = 64;                      // chunks per stripe
  const int S = (C + cps - 1) / cps;       // 25 stripes -> 16x25 = 400 blocks
  k_gemm<<<dim3(B / 128, S), 256, 0, stream>>>(qb, xb, aug, cmin, C, cps);

  k_tau<<<B, 64, 0, stream>>>(cmin, tau, kptr, C);
  k_pairs<<<dim3((C + 255) / 256, B), 256, 0, stream>>>(cmin, tau, ccnt, clist, C, B);
  k_exact<<<C, 256, 0, stream>>>(X, xt, aug, q2, tau, ccnt, clist, qcnt, cand, n, B);
  k_final<<<B, 64, 0, stream>>>(w, wmax_u, cand, qcnt, kptr, (float*)d_out, B, n);
}

// Round 2
// 305.100 us; speedup vs baseline: 1.4800x; 1.4800x over previous
//
#include <hip/hip_runtime.h>
#include <stdint.h>

typedef short   shortx8 __attribute__((ext_vector_type(8)));
typedef float   f32x4   __attribute__((ext_vector_type(4)));

static __device__ __forceinline__ unsigned short f2bf(float f) {
  unsigned u = __float_as_uint(f);
  unsigned r = u + 0x7FFFu + ((u >> 16) & 1u);   // RTNE
  return (unsigned short)(r >> 16);
}

static __device__ __forceinline__ void gl2lds16(const void* gsrc, void* ldst) {
  __builtin_amdgcn_global_load_lds(
      (const __attribute__((address_space(1))) unsigned int*)gsrc,
      (__attribute__((address_space(3))) unsigned int*)ldst, 16, 0, 0);
}

// ---------------- K0: wmax = max(relu(w)) ----------------
__global__ void k_wmax(const float* __restrict__ w, int n, unsigned* __restrict__ wmax_u) {
  int i = blockIdx.x * 256 + threadIdx.x;
  float v = 0.f;
  if (i < n) v = fmaxf(w[i], 0.f);
  for (int m = 32; m; m >>= 1) v = fmaxf(v, __shfl_xor(v, m));
  if ((threadIdx.x & 63) == 0) atomicMax(wmax_u, __float_as_uint(v));
}

// ---------------- K1: fused X->bf16 + aug[n] = ||x||^2 + wmax - w  (one X pass) ----
__global__ void k_prep(const float* __restrict__ X, const float* __restrict__ w,
                       const unsigned* __restrict__ wmax_u, unsigned short* __restrict__ xb,
                       float* __restrict__ aug, int n, int npad) {
  int r = blockIdx.x * 4 + (threadIdx.x >> 6);
  int lane = threadIdx.x & 63;
  if (r >= npad) return;
  if (r < n) {
    float a = X[(size_t)r * 128 + lane];
    float b = X[(size_t)r * 128 + 64 + lane];
    xb[(size_t)r * 128 + lane] = f2bf(a);
    xb[(size_t)r * 128 + 64 + lane] = f2bf(b);
    float s = a * a + b * b;                    // same pairing as R1 (numerics kept)
    for (int m = 32; m; m >>= 1) s += __shfl_xor(s, m);
    if (lane == 0) aug[r] = s + __uint_as_float(*wmax_u) - w[r];
  } else {
    xb[(size_t)r * 128 + lane] = 0;
    xb[(size_t)r * 128 + 64 + lane] = 0;
    if (lane == 0) aug[r] = 1e30f;
  }
}

// ---------------- K1c: queries -> bf16, q2 = ||q||^2 ----------------
__global__ void k_q(const float* __restrict__ xt, unsigned short* __restrict__ qb,
                    float* __restrict__ q2, int B) {
  int r = blockIdx.x * 4 + (threadIdx.x >> 6);
  int lane = threadIdx.x & 63;
  if (r >= B) return;
  float a = xt[(size_t)r * 128 + lane];
  float b = xt[(size_t)r * 128 + 64 + lane];
  qb[(size_t)r * 128 + lane] = f2bf(a);
  qb[(size_t)r * 128 + 64 + lane] = f2bf(b);
  float s = a * a + b * b;
  for (int m = 32; m; m >>= 1) s += __shfl_xor(s, m);
  if (lane == 0) q2[r] = s;
}

// ---------------- K2: bf16 MFMA -> per-(query,chunk64) min, D[db][query] layout ----
// 2-phase pipeline: global_load_lds (pre-swizzled source), 1 barrier/chunk.
#define CPS 16
__global__ __launch_bounds__(256) void k_gemm(const unsigned short* __restrict__ qb,
    const unsigned short* __restrict__ xb, const float* __restrict__ aug,
    float* __restrict__ cmin, int C) {
  __shared__ __align__(16) unsigned short tile[2][8192];   // 2 x 16KB (64 rows x 128)
  const int t = threadIdx.x;
  const int lane = t & 63, wv = t >> 6;
  const int li = lane & 15, lg = lane >> 4;
  const int qbase = blockIdx.x * 128 + wv * 32;

  // B operand: 32 queries x K=128, resident in registers
  shortx8 qf[2][4];
#pragma unroll
  for (int qt = 0; qt < 2; ++qt)
#pragma unroll
    for (int ks = 0; ks < 4; ++ks)
      qf[qt][ks] = *(const shortx8*)(qb + (size_t)(qbase + qt * 16 + li) * 128 + ks * 32 + lg * 8);

  // per-lane pre-swizzled source byte offsets (rule #21: linear LDS dest,
  // inverse-swizzled global source, swizzled ds_read)
  int soff[4];
#pragma unroll
  for (int j = 0; j < 4; ++j) {
    int o = wv * 4096 + j * 1024 + lane * 16;
    int r = o >> 8;                               // 256 B per row
    soff[j] = (o & ~255) | ((o & 255) ^ ((r & 7) << 4));
  }

  const int c0 = blockIdx.y * CPS;
  const int c1 = min(c0 + CPS, C);

#define STAGE(buf, cc) do {                                                  \
    const char* _s = (const char*)xb + (size_t)(cc) * 16384;                 \
    _Pragma("unroll")                                                        \
    for (int _j = 0; _j < 4; ++_j)                                           \
      gl2lds16(_s + soff[_j], &tile[buf][wv * 2048 + _j * 512]);             \
  } while (0)

  STAGE(0, c0);
  __syncthreads();                                // drain: chunk c0 resident

  for (int c = c0; c < c1; ++c) {
    const int cur = (c - c0) & 1;
    if (c + 1 < c1) STAGE(cur ^ 1, c + 1);        // async, overlaps compute

    f32x4 acc[4][2];
#pragma unroll
    for (int rg = 0; rg < 4; ++rg)
#pragma unroll
      for (int qt = 0; qt < 2; ++qt)
        acc[rg][qt] = (f32x4){0.f, 0.f, 0.f, 0.f};

#pragma unroll
    for (int rg = 0; rg < 4; ++rg) {
      const int r = rg * 16 + li;
      const int rsw = (r & 7) << 3;               // element-unit swizzle
      shortx8 af[4];
#pragma unroll
      for (int ks = 0; ks < 4; ++ks)
        af[ks] = *(const shortx8*)(&tile[cur][r * 128 + ((ks * 32 + lg * 8) ^ rsw)]);
#pragma unroll
      for (int qt = 0; qt < 2; ++qt)
#pragma unroll
        for (int ks = 0; ks < 4; ++ks)
          acc[rg][qt] = __builtin_amdgcn_mfma_f32_16x16x32_bf16(af[ks], qf[qt][ks], acc[rg][qt], 0, 0, 0);
    }

    // v = aug - 2*dot; per-lane min over rg,p then shfl over lg (masks 16,32)
    float m0 = 1e38f, m1 = 1e38f;
#pragma unroll
    for (int rg = 0; rg < 4; ++rg) {
      f32x4 av = *(const f32x4*)(aug + c * 64 + rg * 16 + lg * 4);
#pragma unroll
      for (int p = 0; p < 4; ++p) {
        m0 = fminf(m0, fmaf(-2.f, acc[rg][0][p], av[p]));
        m1 = fminf(m1, fmaf(-2.f, acc[rg][1][p], av[p]));
      }
    }
    m0 = fminf(m0, __shfl_xor(m0, 16)); m0 = fminf(m0, __shfl_xor(m0, 32));
    m1 = fminf(m1, __shfl_xor(m1, 16)); m1 = fminf(m1, __shfl_xor(m1, 32));
    if (lane < 16) {
      cmin[(size_t)(qbase + li) * C + c] = m0;
      cmin[(size_t)(qbase + 16 + li) * C + c] = m1;
    }
    __syncthreads();                              // drains prefetch; cur reusable
  }
#undef STAGE
}

// ---------------- K3: tau = (k-th smallest chunk-min)+1.5, fused pair append ----
__global__ void k_tau(const float* __restrict__ cmin, float* __restrict__ tau,
                      const int* __restrict__ kptr, int* __restrict__ ccnt,
                      int* __restrict__ clist, int C, int B) {
  __shared__ float arr[2048];
  const int q = blockIdx.x, t = threadIdx.x;
  const float* row = cmin + (size_t)q * C;
  float lmd = 1e38f; int lmi = 0x7fffffff;
  for (int i = t; i < C; i += 64) {
    float v = row[i]; arr[i] = v;
    if (v < lmd) { lmd = v; lmi = i; }
  }
  int k = *kptr; if (k < 1) k = 1; if (k > 32) k = 32;
  float tv = 1e38f;
  for (int r = 0; r < k; ++r) {
    float md = lmd; int mi = lmi;
    for (int msk = 32; msk; msk >>= 1) {
      float od = __shfl_xor(md, msk); int oi = __shfl_xor(mi, msk);
      if (od < md || (od == md && oi < mi)) { md = od; mi = oi; }
    }
    tv = md;
    if (r + 1 < k && (mi & 63) == t) {            // owner removes + rescans
      arr[mi] = 1e38f;
      lmd = 1e38f; lmi = 0x7fffffff;
      for (int i = t; i < C; i += 64) {
        float v = arr[i];
        if (v < lmd) { lmd = v; lmi = i; }
      }
    }
  }
  const float tq = tv + 1.5f;
  if (t == 0) tau[q] = tq;
  for (int i = t; i < C; i += 64)                 // append from (L2-hot) global row
    if (row[i] <= tq) {
      int pos = atomicAdd(&ccnt[i], 1);
      clist[(size_t)i * B + pos] = q;
    }
}

// ---------------- K4: exact fp32 recompute for selected (query, chunk) pairs ----
__global__ __launch_bounds__(256) void k_exact(const float* __restrict__ X, const float* __restrict__ xt,
    const float* __restrict__ aug, const float* __restrict__ q2, const float* __restrict__ tau,
    const int* __restrict__ ccnt, const int* __restrict__ clist,
    int* __restrict__ qcnt, float2* __restrict__ cand, int n, int B) {
  const int c = blockIdx.x;
  const int nq = ccnt[c];
  if (nq == 0) return;
  __shared__ float xs[64 * 129];
  __shared__ float qs[4][128];
  const int t = threadIdx.x;
  for (int i = t; i < 8192; i += 256) {
    int r = i >> 7, cc = i & 127;
    long g = (long)c * 64 + r;
    xs[r * 129 + cc] = (g < n) ? X[g * 128 + cc] : 0.f;
  }
  __syncthreads();
  const int wv = t >> 6, lane = t & 63;
  const int gcol = c * 64 + lane;
  const float augv = aug[gcol];
  for (int i = wv; i < nq; i += 4) {
    const int q = clist[(size_t)c * B + i];
    qs[wv][lane] = xt[(size_t)q * 128 + lane];
    qs[wv][64 + lane] = xt[(size_t)q * 128 + 64 + lane];
    __asm__ volatile("s_waitcnt lgkmcnt(0)" ::: "memory");
    float a0 = 0.f, a1 = 0.f, a2 = 0.f, a3 = 0.f;
#pragma unroll
    for (int kk = 0; kk < 128; kk += 4) {
      a0 = fmaf(qs[wv][kk],     xs[lane * 129 + kk],     a0);
      a1 = fmaf(qs[wv][kk + 1], xs[lane * 129 + kk + 1], a1);
      a2 = fmaf(qs[wv][kk + 2], xs[lane * 129 + kk + 2], a2);
      a3 = fmaf(qs[wv][kk + 3], xs[lane * 129 + kk + 3], a3);
    }
    const float acc = (a0 + a1) + (a2 + a3);
    const float s = fmaf(-2.f, acc, augv);
    if (gcol < n && s <= tau[q]) {
      int pos = atomicAdd(&qcnt[q], 1);
      if (pos < 256) {
        float d2 = (q2[q] - 2.f * acc) + augv;
        cand[(size_t)q * 256 + pos] = make_float2(d2, __int_as_float(gcol));
      }
    }
  }
}

// ---------------- K5: exact top-k (ascending (d2,idx)) + argmax f ----------------
__global__ void k_final(const float* __restrict__ w, const unsigned* __restrict__ wmax_u,
    const float2* __restrict__ cand, const int* __restrict__ qcnt, const int* __restrict__ kptr,
    float* __restrict__ dout, int B, int n) {
  const int q = blockIdx.x, lane = threadIdx.x;
  int k = *kptr; if (k < 1) k = 1; if (k > 64) k = 64;
  const float wmax = __uint_as_float(*wmax_u);
  const int cnt = min(qcnt[q], 256);
  float d0 = 1e38f, d1 = 1e38f, d2v = 1e38f, d3 = 1e38f;
  int i0 = 0x7fffffff, i1 = 0x7fffffff, i2 = 0x7fffffff, i3 = 0x7fffffff;
  {
    int s;
    s = lane;       if (s < cnt) { float2 cc = cand[(size_t)q * 256 + s]; d0 = cc.x; i0 = __float_as_int(cc.y); }
    s = lane + 64;  if (s < cnt) { float2 cc = cand[(size_t)q * 256 + s]; d1 = cc.x; i1 = __float_as_int(cc.y); }
    s = lane + 128; if (s < cnt) { float2 cc = cand[(size_t)q * 256 + s]; d2v = cc.x; i2 = __float_as_int(cc.y); }
    s = lane + 192; if (s < cnt) { float2 cc = cand[(size_t)q * 256 + s]; d3 = cc.x; i3 = __float_as_int(cc.y); }
  }
  float bestf = -1e38f; int besti = 0;
  for (int r = 0; r < k; ++r) {
    float md = d0; int mi = i0; int mj = 0;
    if (d1 < md || (d1 == md && i1 < mi)) { md = d1; mi = i1; mj = 1; }
    if (d2v < md || (d2v == md && i2 < mi)) { md = d2v; mi = i2; mj = 2; }
    if (d3 < md || (d3 == md && i3 < mi)) { md = d3; mi = i3; mj = 3; }
    int ml = lane;
    for (int msk = 32; msk; msk >>= 1) {
      float od = __shfl_xor(md, msk); int oi = __shfl_xor(mi, msk);
      int ol = __shfl_xor(ml, msk);   int oj = __shfl_xor(mj, msk);
      if (od < md || (od == md && oi < mi)) { md = od; mi = oi; ml = ol; mj = oj; }
    }
    if (lane == ml) {
      if (mj == 0)      { d0 = 1e38f;  i0 = 0x7fffffff; }
      else if (mj == 1) { d1 = 1e38f;  i1 = 0x7fffffff; }
      else if (mj == 2) { d2v = 1e38f; i2 = 0x7fffffff; }
      else              { d3 = 1e38f;  i3 = 0x7fffffff; }
    }
    if (mi >= 0 && mi < n) {
      float wi = w[mi];
      float da = sqrtf(fmaxf(md - (wmax - wi), 0.f));
      float f = wi - da;
      if (f > bestf) { bestf = f; besti = mi; }
    }
  }
  if (lane == 0) { dout[q] = bestf; dout[B + q] = (float)besti; }
}

extern "C" void kernel_launch(void* const* d_in, const int* in_sizes, int n_in,
                              void* d_out, int out_size, void* d_ws, size_t ws_size,
                              hipStream_t stream) {
  const float* xt = (const float*)d_in[0];
  const float* X  = (const float*)d_in[1];
  const float* w  = (const float*)d_in[2];
  const int* kptr = (const int*)d_in[3];
  const int B = in_sizes[0] / 128;        // 2048
  const int n = in_sizes[2];              // 100000
  const int C = (n + 63) / 64;            // 1563 chunks of 64
  const int npad = C * 64;

  char* ws = (char*)d_ws;
  const size_t o_wmax = 0, o_ccnt = 1024, o_qcnt = 8192;
  const size_t o_q2   = 16384;
  const size_t o_tau  = o_q2 + (size_t)B * 4;
  const size_t o_aug  = o_tau + (size_t)B * 4;
  const size_t o_cmin = (o_aug + (size_t)npad * 4 + 255) & ~(size_t)255;
  const size_t o_clist= (o_cmin + (size_t)B * C * 4 + 255) & ~(size_t)255;
  const size_t o_cand = (o_clist + (size_t)C * B * 4 + 255) & ~(size_t)255;
  const size_t o_qb   = (o_cand + (size_t)B * 256 * 8 + 255) & ~(size_t)255;
  const size_t o_xb   = (o_qb + (size_t)B * 128 * 2 + 255) & ~(size_t)255;

  unsigned* wmax_u = (unsigned*)(ws + o_wmax);
  int* ccnt  = (int*)(ws + o_ccnt);
  int* qcnt  = (int*)(ws + o_qcnt);
  float* q2  = (float*)(ws + o_q2);
  float* tau = (float*)(ws + o_tau);
  float* aug = (float*)(ws + o_aug);
  float* cmin = (float*)(ws + o_cmin);
  int* clist = (int*)(ws + o_clist);
  float2* cand = (float2*)(ws + o_cand);
  unsigned short* qb = (unsigned short*)(ws + o_qb);
  unsigned short* xb = (unsigned short*)(ws + o_xb);

  hipMemsetAsync(d_ws, 0, 16384, stream);  // wmax + ccnt + qcnt

  k_wmax<<<(n + 255) / 256, 256, 0, stream>>>(w, n, wmax_u);
  k_prep<<<(npad + 3) / 4, 256, 0, stream>>>(X, w, wmax_u, xb, aug, n, npad);
  k_q<<<(B + 3) / 4, 256, 0, stream>>>(xt, qb, q2, B);

  const int S = (C + CPS - 1) / CPS;       // 98 stripes -> 16x98 = 1568 blocks
  k_gemm<<<dim3(B / 128, S), 256, 0, stream>>>(qb, xb, aug, cmin, C);

  k_tau<<<B, 64, 0, stream>>>(cmin, tau, kptr, ccnt, clist, C, B);
  k_exact<<<C, 256, 0, stream>>>(X, xt, aug, q2, tau, ccnt, clist, qcnt, cand, n, B);
  k_final<<<B, 64, 0, stream>>>(w, wmax_u, cand, qcnt, kptr, (float*)d_out, B, n);
}

// Round 4
// 304.543 us; speedup vs baseline: 1.4827x; 1.0018x over previous
//
#include <hip/hip_runtime.h>
#include <stdint.h>

typedef short   shortx8 __attribute__((ext_vector_type(8)));
typedef float   f32x4   __attribute__((ext_vector_type(4)));

#define CPS 16

static __device__ __forceinline__ unsigned short f2bf(float f) {
  unsigned u = __float_as_uint(f);
  unsigned r = u + 0x7FFFu + ((u >> 16) & 1u);   // RTNE
  return (unsigned short)(r >> 16);
}

static __device__ __forceinline__ void gl2lds16(const void* gsrc, void* ldst) {
  __builtin_amdgcn_global_load_lds(
      (const __attribute__((address_space(1))) unsigned int*)gsrc,
      (__attribute__((address_space(3))) unsigned int*)ldst, 16, 0, 0);
}

// ---- K1: fused {X->bf16, aug = ||x||^2 - w} and {xt->bf16, q2} (wmax eliminated:
//      uniform +wmax shift cancels in ranking, filtering, and both outputs) ----
__global__ void k_prep(const float* __restrict__ X, const float* __restrict__ xt,
                       const float* __restrict__ w, unsigned short* __restrict__ xb,
                       unsigned short* __restrict__ qb, float* __restrict__ aug,
                       float* __restrict__ q2, int n, int npad, int xblocks, int B) {
  const int wv = threadIdx.x >> 6, lane = threadIdx.x & 63;
  if ((int)blockIdx.x < xblocks) {
    int r = blockIdx.x * 4 + wv;
    if (r >= npad) return;
    if (r < n) {
      float2 v = *(const float2*)(X + (size_t)r * 128 + lane * 2);
      unsigned pk = (unsigned)f2bf(v.x) | ((unsigned)f2bf(v.y) << 16);
      *(unsigned*)(xb + (size_t)r * 128 + lane * 2) = pk;
      float s = v.x * v.x + v.y * v.y;
      for (int m = 32; m; m >>= 1) s += __shfl_xor(s, m);
      if (lane == 0) aug[r] = s - w[r];
    } else {
      *(unsigned*)(xb + (size_t)r * 128 + lane * 2) = 0;
      if (lane == 0) aug[r] = 1e30f;
    }
  } else {
    int r = (blockIdx.x - xblocks) * 4 + wv;
    if (r >= B) return;
    float2 v = *(const float2*)(xt + (size_t)r * 128 + lane * 2);
    unsigned pk = (unsigned)f2bf(v.x) | ((unsigned)f2bf(v.y) << 16);
    *(unsigned*)(qb + (size_t)r * 128 + lane * 2) = pk;
    float s = v.x * v.x + v.y * v.y;
    for (int m = 32; m; m >>= 1) s += __shfl_xor(s, m);
    if (lane == 0) q2[r] = s;
  }
}

// ---- K2: bf16 MFMA -> per-(query,chunk64) min of s' = aug - 2*dot ----
// 64 q/wave (qt=4), reg-accumulated cmin + coalesced LDS-bounce write,
// aug prefetch, XCD-bijective stripe swizzle, full 16-chunk unroll.
__global__ __launch_bounds__(256, 2) void k_gemm(const unsigned short* __restrict__ qb,
    const unsigned short* __restrict__ xb, const float* __restrict__ aug,
    float* __restrict__ cmin, int C) {
  __shared__ __align__(16) unsigned short tile[2][8192];   // 2 x 16KB; reused as out-bounce
  const int S = C / CPS;                     // 98 stripes
  const int b = blockIdx.x;
  const int xcd = b & 7;
  const int j = b >> 3;                      // 0..103
  const int sj = j % 13, xq = j / 13;        // xq 0..7
  const int qq = S >> 3, rr = S & 7;         // m204 bijective split: 12, 2
  const int nst = (xcd < rr) ? (qq + 1) : qq;
  if (sj >= nst) return;
  const int ystripe = (xcd < rr) ? (xcd * (qq + 1) + sj)
                                 : (rr * (qq + 1) + (xcd - rr) * qq + sj);
  const int c0 = ystripe * CPS;

  const int t = threadIdx.x;
  const int lane = t & 63, wv = t >> 6;
  const int li = lane & 15, lg = lane >> 4;
  const int qbase = xq * 256 + wv * 64;

  // B operand: 64 queries x K=128 resident in registers
  shortx8 qf[4][4];
#pragma unroll
  for (int qt = 0; qt < 4; ++qt)
#pragma unroll
    for (int ks = 0; ks < 4; ++ks)
      qf[qt][ks] = *(const shortx8*)(qb + (size_t)(qbase + qt * 16 + li) * 128 + ks * 32 + lg * 8);

  // pre-swizzled global source offsets (linear LDS dest, swizzled ds_read)
  int soff[4];
#pragma unroll
  for (int jj = 0; jj < 4; ++jj) {
    int o = wv * 4096 + jj * 1024 + lane * 16;
    int r = o >> 8;
    soff[jj] = (o & ~255) | ((o & 255) ^ ((r & 7) << 4));
  }

#define STAGE(buf, cc) do {                                                  \
    const char* _s = (const char*)xb + (size_t)(cc) * 16384;                 \
    _Pragma("unroll")                                                        \
    for (int _j = 0; _j < 4; ++_j)                                           \
      gl2lds16(_s + soff[_j], &tile[buf][wv * 2048 + _j * 512]);             \
  } while (0)

  float cm[4][4];      // [qt][chunk>>2], owner lane: lg == chunk&3
#pragma unroll
  for (int qt = 0; qt < 4; ++qt)
#pragma unroll
    for (int jj = 0; jj < 4; ++jj) cm[qt][jj] = 1e38f;

  f32x4 av[2][4];
#pragma unroll
  for (int rg = 0; rg < 4; ++rg)
    av[0][rg] = *(const f32x4*)(aug + (size_t)c0 * 64 + rg * 16 + lg * 4);

  STAGE(0, c0);
  __syncthreads();

#pragma unroll
  for (int cc = 0; cc < CPS; ++cc) {
    const int cur = cc & 1;
    if (cc + 1 < CPS) {
      STAGE(cur ^ 1, c0 + cc + 1);
#pragma unroll
      for (int rg = 0; rg < 4; ++rg)
        av[cur ^ 1][rg] = *(const f32x4*)(aug + (size_t)(c0 + cc + 1) * 64 + rg * 16 + lg * 4);
    }

    f32x4 acc[4][4];
#pragma unroll
    for (int rg = 0; rg < 4; ++rg)
#pragma unroll
      for (int qt = 0; qt < 4; ++qt)
        acc[rg][qt] = (f32x4){0.f, 0.f, 0.f, 0.f};

#pragma unroll
    for (int rg = 0; rg < 4; ++rg) {
      const int r = rg * 16 + li;
      const int rsw = (r & 7) << 3;
      shortx8 af[4];
#pragma unroll
      for (int ks = 0; ks < 4; ++ks)
        af[ks] = *(const shortx8*)(&tile[cur][r * 128 + ((ks * 32 + lg * 8) ^ rsw)]);
#pragma unroll
      for (int qt = 0; qt < 4; ++qt)
#pragma unroll
        for (int ks = 0; ks < 4; ++ks)
          acc[rg][qt] = __builtin_amdgcn_mfma_f32_16x16x32_bf16(af[ks], qf[qt][ks], acc[rg][qt], 0, 0, 0);
    }

    float m[4];
#pragma unroll
    for (int qt = 0; qt < 4; ++qt) {
      float v = 1e38f;
#pragma unroll
      for (int rg = 0; rg < 4; ++rg)
#pragma unroll
        for (int p = 0; p < 4; ++p)
          v = fminf(v, fmaf(-2.f, acc[rg][qt][p], av[cur][rg][p]));
      v = fminf(v, __shfl_xor(v, 16));
      v = fminf(v, __shfl_xor(v, 32));
      m[qt] = v;
    }
#pragma unroll
    for (int qt = 0; qt < 4; ++qt)
      cm[qt][cc >> 2] = (lg == (cc & 3)) ? m[qt] : cm[qt][cc >> 2];

    __syncthreads();
  }
#undef STAGE

  // coalesced cmin write via LDS bounce (stride 20 floats: 2-way banks, b128-aligned)
  float* outf = (float*)tile;
#pragma unroll
  for (int qt = 0; qt < 4; ++qt)
#pragma unroll
    for (int jj = 0; jj < 4; ++jj)
      outf[(wv * 64 + qt * 16 + li) * 20 + jj * 4 + lg] = cm[qt][jj];
  __syncthreads();
#pragma unroll
  for (int p = 0; p < 4; ++p) {
    int flat = p * 1024 + t * 4;
    int ql = flat >> 4, cix = flat & 15;
    f32x4 v = *(const f32x4*)&outf[ql * 20 + cix];
    *(f32x4*)&cmin[(size_t)(xq * 256 + ql) * C + c0 + cix] = v;
  }
}

// ---- K3: tau = (k-th smallest chunk-min)+1.5, fused per-chunk list append ----
__global__ void k_tau(const float* __restrict__ cmin, float* __restrict__ tau,
                      const int* __restrict__ kptr, int* __restrict__ ccnt,
                      int* __restrict__ clist, int C, int B) {
  __shared__ float arr[1600];
  __shared__ float red[4];
  __shared__ int   redi[4];
  __shared__ float bval;
  __shared__ int   bidx;
  const int q = blockIdx.x, t = threadIdx.x;
  const int lane = t & 63, wv = t >> 6;
  const float* row = cmin + (size_t)q * C;
  float lmd = 1e38f; int lmi = -1;
  for (int i = t; i < C; i += 256) {
    float v = row[i]; arr[i] = v;
    if (v < lmd) { lmd = v; lmi = i; }
  }
  __syncthreads();
  int k = *kptr; if (k < 1) k = 1; if (k > 32) k = 32;
  float tv = 1e38f;
  for (int r = 0; r < k; ++r) {
    float md = lmd; int mi = lmi;
    for (int msk = 32; msk; msk >>= 1) {
      float od = __shfl_xor(md, msk); int oi = __shfl_xor(mi, msk);
      if (od < md) { md = od; mi = oi; }
    }
    if (lane == 0) { red[wv] = md; redi[wv] = mi; }
    __syncthreads();
    if (t == 0) {
      float bm = red[0]; int bi = redi[0];
      for (int u = 1; u < 4; ++u) if (red[u] < bm) { bm = red[u]; bi = redi[u]; }
      bval = bm; bidx = bi;
    }
    __syncthreads();
    tv = bval;
    const int sel = bidx;
    if (r + 1 < k && sel >= 0 && (sel & 255) == t) {
      arr[sel] = 1e38f;
      lmd = 1e38f; lmi = -1;
      for (int i = t; i < C; i += 256) {
        float v = arr[i];
        if (v < lmd) { lmd = v; lmi = i; }
      }
    }
    __syncthreads();
  }
  const float tq = tv + 1.5f;
  if (t == 0) tau[q] = tq;
  for (int i = t; i < C; i += 256)
    if (row[i] <= tq) {
      int pos = atomicAdd(&ccnt[i], 1);
      clist[(size_t)i * B + pos] = q;
    }
}

// ---- K4: exact fp32 recompute, 16 queries per pass (4/wave) ----
__global__ __launch_bounds__(256) void k_exact(const float* __restrict__ X, const float* __restrict__ xt,
    const float* __restrict__ aug, const float* __restrict__ q2, const float* __restrict__ tau,
    const int* __restrict__ ccnt, const int* __restrict__ clist,
    int* __restrict__ qcnt, float2* __restrict__ cand, int n, int B) {
  const int c = blockIdx.x;
  const int nq = ccnt[c];
  if (nq == 0) return;
  __shared__ float xs[64 * 132];
  __shared__ float qs[16][128];
  __shared__ int   qid[16];
  __shared__ float qtau[16], qq2[16];
  const int t = threadIdx.x, lane = t & 63, wv = t >> 6;
#pragma unroll
  for (int p = 0; p < 8; ++p) {
    int flat = p * 1024 + t * 4;
    int r = flat >> 7, col = flat & 127;
    long g = (long)c * 64 + r;
    f32x4 v = (f32x4){0.f, 0.f, 0.f, 0.f};
    if (g < n) v = *(const f32x4*)(X + g * 128 + col);
    *(f32x4*)&xs[r * 132 + col] = v;
  }
  const int gcol = c * 64 + lane;
  const float augv = aug[gcol];
  __syncthreads();
  const int qrow = t >> 4, qcol = (t & 15) * 8;
  for (int i0 = 0; i0 < nq; i0 += 16) {
    int qidx = i0 + qrow;
    int qn = (qidx < nq) ? clist[(size_t)c * B + qidx] : -1;
    if (qn >= 0) {
      *(f32x4*)&qs[qrow][qcol]     = *(const f32x4*)(xt + (size_t)qn * 128 + qcol);
      *(f32x4*)&qs[qrow][qcol + 4] = *(const f32x4*)(xt + (size_t)qn * 128 + qcol + 4);
    }
    if ((t & 15) == 0) {
      qid[qrow] = qn;
      qtau[qrow] = (qn >= 0) ? tau[qn] : -1e38f;
      qq2[qrow] = (qn >= 0) ? q2[qn] : 0.f;
    }
    __syncthreads();
    float a0 = 0.f, a1 = 0.f, a2 = 0.f, a3 = 0.f;
#pragma unroll
    for (int kk = 0; kk < 128; kk += 4) {
      f32x4 xv = *(const f32x4*)&xs[lane * 132 + kk];
      f32x4 u0 = *(const f32x4*)&qs[wv * 4 + 0][kk];
      f32x4 u1 = *(const f32x4*)&qs[wv * 4 + 1][kk];
      f32x4 u2 = *(const f32x4*)&qs[wv * 4 + 2][kk];
      f32x4 u3 = *(const f32x4*)&qs[wv * 4 + 3][kk];
#pragma unroll
      for (int e = 0; e < 4; ++e) {
        a0 = fmaf(xv[e], u0[e], a0);
        a1 = fmaf(xv[e], u1[e], a1);
        a2 = fmaf(xv[e], u2[e], a2);
        a3 = fmaf(xv[e], u3[e], a3);
      }
    }
#pragma unroll
    for (int u = 0; u < 4; ++u) {
      const float accv = (u == 0) ? a0 : (u == 1) ? a1 : (u == 2) ? a2 : a3;
      const int qr = wv * 4 + u;
      const int qn2 = qid[qr];
      const float s = fmaf(-2.f, accv, augv);
      if (qn2 >= 0 && gcol < n && s <= qtau[qr]) {
        int pos = atomicAdd(&qcnt[qn2], 1);
        if (pos < 256) {
          float d2 = fmaf(-2.f, accv, qq2[qr]) + augv;
          cand[(size_t)qn2 * 256 + pos] = make_float2(d2, __int_as_float(gcol));
        }
      }
    }
    __syncthreads();
  }
}

// ---- K5: exact top-k (ascending (d2',idx)) + argmax f; f = w - sqrt(relu(d2'+w)) ----
__global__ void k_final(const float* __restrict__ w,
    const float2* __restrict__ cand, const int* __restrict__ qcnt, const int* __restrict__ kptr,
    float* __restrict__ dout, int B, int n) {
  const int q = blockIdx.x, lane = threadIdx.x;
  int k = *kptr; if (k < 1) k = 1; if (k > 64) k = 64;
  const int cnt = min(qcnt[q], 256);
  float d0 = 1e38f, d1 = 1e38f, d2v = 1e38f, d3 = 1e38f;
  int i0 = 0x7fffffff, i1 = 0x7fffffff, i2 = 0x7fffffff, i3 = 0x7fffffff;
  {
    int s;
    s = lane;       if (s < cnt) { float2 cc = cand[(size_t)q * 256 + s]; d0 = cc.x; i0 = __float_as_int(cc.y); }
    s = lane + 64;  if (s < cnt) { float2 cc = cand[(size_t)q * 256 + s]; d1 = cc.x; i1 = __float_as_int(cc.y); }
    s = lane + 128; if (s < cnt) { float2 cc = cand[(size_t)q * 256 + s]; d2v = cc.x; i2 = __float_as_int(cc.y); }
    s = lane + 192; if (s < cnt) { float2 cc = cand[(size_t)q * 256 + s]; d3 = cc.x; i3 = __float_as_int(cc.y); }
  }
  float bestf = -1e38f; int besti = 0;
  for (int r = 0; r < k; ++r) {
    float md = d0; int mi = i0; int mj = 0;
    if (d1 < md || (d1 == md && i1 < mi)) { md = d1; mi = i1; mj = 1; }
    if (d2v < md || (d2v == md && i2 < mi)) { md = d2v; mi = i2; mj = 2; }
    if (d3 < md || (d3 == md && i3 < mi)) { md = d3; mi = i3; mj = 3; }
    int ml = lane;
    for (int msk = 32; msk; msk >>= 1) {
      float od = __shfl_xor(md, msk); int oi = __shfl_xor(mi, msk);
      int ol = __shfl_xor(ml, msk);   int oj = __shfl_xor(mj, msk);
      if (od < md || (od == md && oi < mi)) { md = od; mi = oi; ml = ol; mj = oj; }
    }
    if (lane == ml) {
      if (mj == 0)      { d0 = 1e38f;  i0 = 0x7fffffff; }
      else if (mj == 1) { d1 = 1e38f;  i1 = 0x7fffffff; }
      else if (mj == 2) { d2v = 1e38f; i2 = 0x7fffffff; }
      else              { d3 = 1e38f;  i3 = 0x7fffffff; }
    }
    if (mi >= 0 && mi < n) {
      float wi = w[mi];
      float da = sqrtf(fmaxf(md + wi, 0.f));
      float f = wi - da;
      if (f > bestf) { bestf = f; besti = mi; }
    }
  }
  if (lane == 0) { dout[q] = bestf; dout[B + q] = (float)besti; }
}

extern "C" void kernel_launch(void* const* d_in, const int* in_sizes, int n_in,
                              void* d_out, int out_size, void* d_ws, size_t ws_size,
                              hipStream_t stream) {
  const float* xt = (const float*)d_in[0];
  const float* X  = (const float*)d_in[1];
  const float* w  = (const float*)d_in[2];
  const int* kptr = (const int*)d_in[3];
  const int B = in_sizes[0] / 128;            // 2048
  const int n = in_sizes[2];                  // 100000
  const int C = ((n + 63) / 64 + CPS - 1) / CPS * CPS;  // 1568 (padded to stripe multiple)
  const int npad = C * 64;                    // 100352

  char* ws = (char*)d_ws;
  const size_t o_ccnt = 0;                                   // C ints (<= 8192 B)
  const size_t o_qcnt = 8192;                                // B ints
  const size_t o_q2   = 16384;
  const size_t o_tau  = o_q2 + (size_t)B * 4;
  const size_t o_aug  = o_tau + (size_t)B * 4;
  const size_t o_cmin = (o_aug + (size_t)npad * 4 + 255) & ~(size_t)255;
  const size_t o_clist= (o_cmin + (size_t)B * C * 4 + 255) & ~(size_t)255;
  const size_t o_cand = (o_clist + (size_t)C * B * 4 + 255) & ~(size_t)255;
  const size_t o_qb   = (o_cand + (size_t)B * 256 * 8 + 255) & ~(size_t)255;
  const size_t o_xb   = (o_qb + (size_t)B * 128 * 2 + 255) & ~(size_t)255;

  int* ccnt  = (int*)(ws + o_ccnt);
  int* qcnt  = (int*)(ws + o_qcnt);
  float* q2  = (float*)(ws + o_q2);
  float* tau = (float*)(ws + o_tau);
  float* aug = (float*)(ws + o_aug);
  float* cmin = (float*)(ws + o_cmin);
  int* clist = (int*)(ws + o_clist);
  float2* cand = (float2*)(ws + o_cand);
  unsigned short* qb = (unsigned short*)(ws + o_qb);
  unsigned short* xb = (unsigned short*)(ws + o_xb);

  hipMemsetAsync(d_ws, 0, 16384, stream);     // ccnt + qcnt

  const int xblocks = npad / 4;
  k_prep<<<xblocks + B / 4, 256, 0, stream>>>(X, xt, w, xb, qb, aug, q2, n, npad, xblocks, B);

  k_gemm<<<832, 256, 0, stream>>>(qb, xb, aug, cmin, C);

  k_tau<<<B, 256, 0, stream>>>(cmin, tau, kptr, ccnt, clist, C, B);
  k_exact<<<C, 256, 0, stream>>>(X, xt, aug, q2, tau, ccnt, clist, qcnt, cand, n, B);
  k_final<<<B, 64, 0, stream>>>(w, cand, qcnt, kptr, (float*)d_out, B, n);
}

// Round 5
// 231.629 us; speedup vs baseline: 1.9494x; 1.3148x over previous
//
#include <hip/hip_runtime.h>
#include <stdint.h>

typedef short   shortx8 __attribute__((ext_vector_type(8)));
typedef float   f32x4   __attribute__((ext_vector_type(4)));

#define CPS 16

static __device__ __forceinline__ unsigned short f2bf(float f) {
  unsigned u = __float_as_uint(f);
  unsigned r = u + 0x7FFFu + ((u >> 16) & 1u);   // RTNE
  return (unsigned short)(r >> 16);
}

static __device__ __forceinline__ void gl2lds16(const void* gsrc, void* ldst) {
  __builtin_amdgcn_global_load_lds(
      (const __attribute__((address_space(1))) unsigned int*)gsrc,
      (__attribute__((address_space(3))) unsigned int*)ldst, 16, 0, 0);
}

// ---- K1: fused {X->bf16, aug = ||x||^2 - w} and {xt->bf16, q2} (wmax eliminated:
//      uniform +wmax shift cancels in ranking, filtering, and both outputs) ----
__global__ void k_prep(const float* __restrict__ X, const float* __restrict__ xt,
                       const float* __restrict__ w, unsigned short* __restrict__ xb,
                       unsigned short* __restrict__ qb, float* __restrict__ aug,
                       float* __restrict__ q2, int n, int npad, int xblocks, int B) {
  const int wv = threadIdx.x >> 6, lane = threadIdx.x & 63;
  if ((int)blockIdx.x < xblocks) {
    int r = blockIdx.x * 4 + wv;
    if (r >= npad) return;
    if (r < n) {
      float2 v = *(const float2*)(X + (size_t)r * 128 + lane * 2);
      unsigned pk = (unsigned)f2bf(v.x) | ((unsigned)f2bf(v.y) << 16);
      *(unsigned*)(xb + (size_t)r * 128 + lane * 2) = pk;
      float s = v.x * v.x + v.y * v.y;
      for (int m = 32; m; m >>= 1) s += __shfl_xor(s, m);
      if (lane == 0) aug[r] = s - w[r];
    } else {
      *(unsigned*)(xb + (size_t)r * 128 + lane * 2) = 0;
      if (lane == 0) aug[r] = 1e30f;
    }
  } else {
    int r = (blockIdx.x - xblocks) * 4 + wv;
    if (r >= B) return;
    float2 v = *(const float2*)(xt + (size_t)r * 128 + lane * 2);
    unsigned pk = (unsigned)f2bf(v.x) | ((unsigned)f2bf(v.y) << 16);
    *(unsigned*)(qb + (size_t)r * 128 + lane * 2) = pk;
    float s = v.x * v.x + v.y * v.y;
    for (int m = 32; m; m >>= 1) s += __shfl_xor(s, m);
    if (lane == 0) q2[r] = s;
  }
}

// ---- K2: bf16 MFMA -> per-(query,chunk64) min of s' = aug - 2*dot ----
// 64 q/wave (qt=4), reg-accumulated cmin + coalesced LDS-bounce write,
// aug prefetch, XCD-bijective stripe swizzle, full 16-chunk unroll.
__global__ __launch_bounds__(256, 2) void k_gemm(const unsigned short* __restrict__ qb,
    const unsigned short* __restrict__ xb, const float* __restrict__ aug,
    float* __restrict__ cmin, int C) {
  __shared__ __align__(16) unsigned short tile[2][8192];   // 2 x 16KB; reused as out-bounce
  const int S = C / CPS;                     // 98 stripes
  const int b = blockIdx.x;
  const int xcd = b & 7;
  const int j = b >> 3;                      // 0..103
  const int sj = j % 13, xq = j / 13;        // xq 0..7
  const int qq = S >> 3, rr = S & 7;         // m204 bijective split: 12, 2
  const int nst = (xcd < rr) ? (qq + 1) : qq;
  if (sj >= nst) return;
  const int ystripe = (xcd < rr) ? (xcd * (qq + 1) + sj)
                                 : (rr * (qq + 1) + (xcd - rr) * qq + sj);
  const int c0 = ystripe * CPS;

  const int t = threadIdx.x;
  const int lane = t & 63, wv = t >> 6;
  const int li = lane & 15, lg = lane >> 4;
  const int qbase = xq * 256 + wv * 64;

  // B operand: 64 queries x K=128 resident in registers
  shortx8 qf[4][4];
#pragma unroll
  for (int qt = 0; qt < 4; ++qt)
#pragma unroll
    for (int ks = 0; ks < 4; ++ks)
      qf[qt][ks] = *(const shortx8*)(qb + (size_t)(qbase + qt * 16 + li) * 128 + ks * 32 + lg * 8);

  // pre-swizzled global source offsets (linear LDS dest, swizzled ds_read)
  int soff[4];
#pragma unroll
  for (int jj = 0; jj < 4; ++jj) {
    int o = wv * 4096 + jj * 1024 + lane * 16;
    int r = o >> 8;
    soff[jj] = (o & ~255) | ((o & 255) ^ ((r & 7) << 4));
  }

#define STAGE(buf, cc) do {                                                  \
    const char* _s = (const char*)xb + (size_t)(cc) * 16384;                 \
    _Pragma("unroll")                                                        \
    for (int _j = 0; _j < 4; ++_j)                                           \
      gl2lds16(_s + soff[_j], &tile[buf][wv * 2048 + _j * 512]);             \
  } while (0)

  float cm[4][4];      // [qt][chunk>>2], owner lane: lg == chunk&3
#pragma unroll
  for (int qt = 0; qt < 4; ++qt)
#pragma unroll
    for (int jj = 0; jj < 4; ++jj) cm[qt][jj] = 1e38f;

  f32x4 av[2][4];
#pragma unroll
  for (int rg = 0; rg < 4; ++rg)
    av[0][rg] = *(const f32x4*)(aug + (size_t)c0 * 64 + rg * 16 + lg * 4);

  STAGE(0, c0);
  __syncthreads();

#pragma unroll
  for (int cc = 0; cc < CPS; ++cc) {
    const int cur = cc & 1;
    if (cc + 1 < CPS) {
      STAGE(cur ^ 1, c0 + cc + 1);
#pragma unroll
      for (int rg = 0; rg < 4; ++rg)
        av[cur ^ 1][rg] = *(const f32x4*)(aug + (size_t)(c0 + cc + 1) * 64 + rg * 16 + lg * 4);
    }

    f32x4 acc[4][4];
#pragma unroll
    for (int rg = 0; rg < 4; ++rg)
#pragma unroll
      for (int qt = 0; qt < 4; ++qt)
        acc[rg][qt] = (f32x4){0.f, 0.f, 0.f, 0.f};

#pragma unroll
    for (int rg = 0; rg < 4; ++rg) {
      const int r = rg * 16 + li;
      const int rsw = (r & 7) << 3;
      shortx8 af[4];
#pragma unroll
      for (int ks = 0; ks < 4; ++ks)
        af[ks] = *(const shortx8*)(&tile[cur][r * 128 + ((ks * 32 + lg * 8) ^ rsw)]);
#pragma unroll
      for (int qt = 0; qt < 4; ++qt)
#pragma unroll
        for (int ks = 0; ks < 4; ++ks)
          acc[rg][qt] = __builtin_amdgcn_mfma_f32_16x16x32_bf16(af[ks], qf[qt][ks], acc[rg][qt], 0, 0, 0);
    }

    float m[4];
#pragma unroll
    for (int qt = 0; qt < 4; ++qt) {
      float v = 1e38f;
#pragma unroll
      for (int rg = 0; rg < 4; ++rg)
#pragma unroll
        for (int p = 0; p < 4; ++p)
          v = fminf(v, fmaf(-2.f, acc[rg][qt][p], av[cur][rg][p]));
      v = fminf(v, __shfl_xor(v, 16));
      v = fminf(v, __shfl_xor(v, 32));
      m[qt] = v;
    }
#pragma unroll
    for (int qt = 0; qt < 4; ++qt)
      cm[qt][cc >> 2] = (lg == (cc & 3)) ? m[qt] : cm[qt][cc >> 2];

    __syncthreads();
  }
#undef STAGE

  // coalesced cmin write via LDS bounce (stride 20 floats: 2-way banks, b128-aligned)
  float* outf = (float*)tile;
#pragma unroll
  for (int qt = 0; qt < 4; ++qt)
#pragma unroll
    for (int jj = 0; jj < 4; ++jj)
      outf[(wv * 64 + qt * 16 + li) * 20 + jj * 4 + lg] = cm[qt][jj];
  __syncthreads();
#pragma unroll
  for (int p = 0; p < 4; ++p) {
    int flat = p * 1024 + t * 4;
    int ql = flat >> 4, cix = flat & 15;
    f32x4 v = *(const f32x4*)&outf[ql * 20 + cix];
    *(f32x4*)&cmin[(size_t)(xq * 256 + ql) * C + c0 + cix] = v;
  }
}

// ---- K3: tau = (k-th smallest chunk-min)+1.5, fused per-chunk list append ----
__global__ void k_tau(const float* __restrict__ cmin, float* __restrict__ tau,
                      const int* __restrict__ kptr, int* __restrict__ ccnt,
                      int* __restrict__ clist, int C, int B) {
  __shared__ float arr[1600];
  __shared__ float red[4];
  __shared__ int   redi[4];
  __shared__ float bval;
  __shared__ int   bidx;
  const int q = blockIdx.x, t = threadIdx.x;
  const int lane = t & 63, wv = t >> 6;
  const float* row = cmin + (size_t)q * C;
  float lmd = 1e38f; int lmi = -1;
  for (int i = t; i < C; i += 256) {
    float v = row[i]; arr[i] = v;
    if (v < lmd) { lmd = v; lmi = i; }
  }
  __syncthreads();
  int k = *kptr; if (k < 1) k = 1; if (k > 32) k = 32;
  float tv = 1e38f;
  for (int r = 0; r < k; ++r) {
    float md = lmd; int mi = lmi;
    for (int msk = 32; msk; msk >>= 1) {
      float od = __shfl_xor(md, msk); int oi = __shfl_xor(mi, msk);
      if (od < md) { md = od; mi = oi; }
    }
    if (lane == 0) { red[wv] = md; redi[wv] = mi; }
    __syncthreads();
    if (t == 0) {
      float bm = red[0]; int bi = redi[0];
      for (int u = 1; u < 4; ++u) if (red[u] < bm) { bm = red[u]; bi = redi[u]; }
      bval = bm; bidx = bi;
    }
    __syncthreads();
    tv = bval;
    const int sel = bidx;
    if (r + 1 < k && sel >= 0 && (sel & 255) == t) {
      arr[sel] = 1e38f;
      lmd = 1e38f; lmi = -1;
      for (int i = t; i < C; i += 256) {
        float v = arr[i];
        if (v < lmd) { lmd = v; lmi = i; }
      }
    }
    __syncthreads();
  }
  const float tq = tv + 1.5f;
  if (t == 0) tau[q] = tq;
  for (int i = t; i < C; i += 256)
    if (row[i] <= tq) {
      int pos = atomicAdd(&ccnt[i], 1);
      clist[(size_t)i * B + pos] = q;
    }
}

// ---- K4: exact fp32 recompute; per-wave independent rounds of 4 queries ----
// X tile: 64x128 fp32, quad-XOR swizzle (quad' = quad ^ (row&31)) => min bank
// aliasing on stage-write and row-read; wave-private q slices in LDS (broadcast
// reads, conflict-free); no block barrier in the main loop; ~64 VGPR.
__global__ __launch_bounds__(256) void k_exact(const float* __restrict__ X, const float* __restrict__ xt,
    const float* __restrict__ aug, const float* __restrict__ q2, const float* __restrict__ tau,
    const int* __restrict__ ccnt, const int* __restrict__ clist,
    int* __restrict__ qcnt, float2* __restrict__ cand, int n, int B) {
  const int c = blockIdx.x;
  const int nq = ccnt[c];
  if (nq == 0) return;
  __shared__ float xs[64 * 128];     // swizzled quads
  __shared__ float qs[4 * 512];      // 4 waves x 4 queries x 128
  const int t = threadIdx.x, lane = t & 63, wv = t >> 6;
#pragma unroll
  for (int p = 0; p < 8; ++p) {
    int flat = p * 1024 + t * 4;
    int r = flat >> 7, col = flat & 127;
    long g = (long)c * 64 + r;
    f32x4 v = (f32x4){0.f, 0.f, 0.f, 0.f};
    if (g < n) v = *(const f32x4*)(X + g * 128 + col);
    *(f32x4*)&xs[r * 128 + ((((col >> 2) ^ (r & 31))) << 2)] = v;
  }
  const int gcol = c * 64 + lane;
  const float augv = aug[gcol];
  __syncthreads();

  float* qsw = qs + wv * 512;
  const int sw = lane & 31;
  const int su = (lane >> 4) & 3;           // staging: which query this lane loads
  const int scol = (lane & 15) * 8;
  for (int i0 = wv * 4; i0 < nq; i0 += 16) {
    const size_t cb = (size_t)c * B;
    int qn0 = __builtin_amdgcn_readfirstlane(clist[cb + min(i0 + 0, nq - 1)]);
    int qn1 = __builtin_amdgcn_readfirstlane(clist[cb + min(i0 + 1, nq - 1)]);
    int qn2 = __builtin_amdgcn_readfirstlane(clist[cb + min(i0 + 2, nq - 1)]);
    int qn3 = __builtin_amdgcn_readfirstlane(clist[cb + min(i0 + 3, nq - 1)]);
    {  // stage this wave's 4 queries (8 floats/lane)
      int qnu = (su == 0) ? qn0 : (su == 1) ? qn1 : (su == 2) ? qn2 : qn3;
      const float* Q = xt + (size_t)qnu * 128 + scol;
      *(f32x4*)&qsw[su * 128 + scol]     = *(const f32x4*)(Q);
      *(f32x4*)&qsw[su * 128 + scol + 4] = *(const f32x4*)(Q + 4);
    }
    float t0 = tau[qn0], t1 = tau[qn1], t2 = tau[qn2], t3 = tau[qn3];
    float g0 = q2[qn0], g1 = q2[qn1], g2 = q2[qn2], g3 = q2[qn3];
    float a0 = 0.f, a1 = 0.f, a2 = 0.f, a3 = 0.f;
#pragma unroll 4
    for (int jj = 0; jj < 32; ++jj) {
      f32x4 xv = *(const f32x4*)&xs[lane * 128 + ((jj ^ sw) << 2)];
      f32x4 v0 = *(const f32x4*)&qsw[0 * 128 + jj * 4];
      f32x4 v1 = *(const f32x4*)&qsw[1 * 128 + jj * 4];
      f32x4 v2 = *(const f32x4*)&qsw[2 * 128 + jj * 4];
      f32x4 v3 = *(const f32x4*)&qsw[3 * 128 + jj * 4];
#pragma unroll
      for (int e = 0; e < 4; ++e) {
        a0 = fmaf(xv[e], v0[e], a0);
        a1 = fmaf(xv[e], v1[e], a1);
        a2 = fmaf(xv[e], v2[e], a2);
        a3 = fmaf(xv[e], v3[e], a3);
      }
    }
#pragma unroll
    for (int u = 0; u < 4; ++u) {
      const float accv = (u == 0) ? a0 : (u == 1) ? a1 : (u == 2) ? a2 : a3;
      const int qnu   = (u == 0) ? qn0 : (u == 1) ? qn1 : (u == 2) ? qn2 : qn3;
      const float tuu = (u == 0) ? t0 : (u == 1) ? t1 : (u == 2) ? t2 : t3;
      const float g2u = (u == 0) ? g0 : (u == 1) ? g1 : (u == 2) ? g2 : g3;
      const float s = fmaf(-2.f, accv, augv);
      if ((i0 + u) < nq && gcol < n && s <= tuu) {
        int pos = atomicAdd(&qcnt[qnu], 1);
        if (pos < 256) {
          float d2v = fmaf(-2.f, accv, g2u) + augv;
          cand[(size_t)qnu * 256 + pos] = make_float2(d2v, __int_as_float(gcol));
        }
      }
    }
  }
}

// ---- K5: exact top-k (ascending (d2',idx)) + argmax f; f = w - sqrt(relu(d2'+w)) ----
__global__ void k_final(const float* __restrict__ w,
    const float2* __restrict__ cand, const int* __restrict__ qcnt, const int* __restrict__ kptr,
    float* __restrict__ dout, int B, int n) {
  const int q = blockIdx.x, lane = threadIdx.x;
  int k = *kptr; if (k < 1) k = 1; if (k > 64) k = 64;
  const int cnt = min(qcnt[q], 256);
  float d0 = 1e38f, d1 = 1e38f, d2v = 1e38f, d3 = 1e38f;
  int i0 = 0x7fffffff, i1 = 0x7fffffff, i2 = 0x7fffffff, i3 = 0x7fffffff;
  {
    int s;
    s = lane;       if (s < cnt) { float2 cc = cand[(size_t)q * 256 + s]; d0 = cc.x; i0 = __float_as_int(cc.y); }
    s = lane + 64;  if (s < cnt) { float2 cc = cand[(size_t)q * 256 + s]; d1 = cc.x; i1 = __float_as_int(cc.y); }
    s = lane + 128; if (s < cnt) { float2 cc = cand[(size_t)q * 256 + s]; d2v = cc.x; i2 = __float_as_int(cc.y); }
    s = lane + 192; if (s < cnt) { float2 cc = cand[(size_t)q * 256 + s]; d3 = cc.x; i3 = __float_as_int(cc.y); }
  }
  float bestf = -1e38f; int besti = 0;
  for (int r = 0; r < k; ++r) {
    float md = d0; int mi = i0; int mj = 0;
    if (d1 < md || (d1 == md && i1 < mi)) { md = d1; mi = i1; mj = 1; }
    if (d2v < md || (d2v == md && i2 < mi)) { md = d2v; mi = i2; mj = 2; }
    if (d3 < md || (d3 == md && i3 < mi)) { md = d3; mi = i3; mj = 3; }
    int ml = lane;
    for (int msk = 32; msk; msk >>= 1) {
      float od = __shfl_xor(md, msk); int oi = __shfl_xor(mi, msk);
      int ol = __shfl_xor(ml, msk);   int oj = __shfl_xor(mj, msk);
      if (od < md || (od == md && oi < mi)) { md = od; mi = oi; ml = ol; mj = oj; }
    }
    if (lane == ml) {
      if (mj == 0)      { d0 = 1e38f;  i0 = 0x7fffffff; }
      else if (mj == 1) { d1 = 1e38f;  i1 = 0x7fffffff; }
      else if (mj == 2) { d2v = 1e38f; i2 = 0x7fffffff; }
      else              { d3 = 1e38f;  i3 = 0x7fffffff; }
    }
    if (mi >= 0 && mi < n) {
      float wi = w[mi];
      float da = sqrtf(fmaxf(md + wi, 0.f));
      float f = wi - da;
      if (f > bestf) { bestf = f; besti = mi; }
    }
  }
  if (lane == 0) { dout[q] = bestf; dout[B + q] = (float)besti; }
}

extern "C" void kernel_launch(void* const* d_in, const int* in_sizes, int n_in,
                              void* d_out, int out_size, void* d_ws, size_t ws_size,
                              hipStream_t stream) {
  const float* xt = (const float*)d_in[0];
  const float* X  = (const float*)d_in[1];
  const float* w  = (const float*)d_in[2];
  const int* kptr = (const int*)d_in[3];
  const int B = in_sizes[0] / 128;            // 2048
  const int n = in_sizes[2];                  // 100000
  const int C = ((n + 63) / 64 + CPS - 1) / CPS * CPS;  // 1568 (padded to stripe multiple)
  const int npad = C * 64;                    // 100352

  char* ws = (char*)d_ws;
  const size_t o_ccnt = 0;                                   // C ints (<= 8192 B)
  const size_t o_qcnt = 8192;                                // B ints
  const size_t o_q2   = 16384;
  const size_t o_tau  = o_q2 + (size_t)B * 4;
  const size_t o_aug  = o_tau + (size_t)B * 4;
  const size_t o_cmin = (o_aug + (size_t)npad * 4 + 255) & ~(size_t)255;
  const size_t o_clist= (o_cmin + (size_t)B * C * 4 + 255) & ~(size_t)255;
  const size_t o_cand = (o_clist + (size_t)C * B * 4 + 255) & ~(size_t)255;
  const size_t o_qb   = (o_cand + (size_t)B * 256 * 8 + 255) & ~(size_t)255;
  const size_t o_xb   = (o_qb + (size_t)B * 128 * 2 + 255) & ~(size_t)255;

  int* ccnt  = (int*)(ws + o_ccnt);
  int* qcnt  = (int*)(ws + o_qcnt);
  float* q2  = (float*)(ws + o_q2);
  float* tau = (float*)(ws + o_tau);
  float* aug = (float*)(ws + o_aug);
  float* cmin = (float*)(ws + o_cmin);
  int* clist = (int*)(ws + o_clist);
  float2* cand = (float2*)(ws + o_cand);
  unsigned short* qb = (unsigned short*)(ws + o_qb);
  unsigned short* xb = (unsigned short*)(ws + o_xb);

  hipMemsetAsync(d_ws, 0, 16384, stream);     // ccnt + qcnt

  const int xblocks = npad / 4;
  k_prep<<<xblocks + B / 4, 256, 0, stream>>>(X, xt, w, xb, qb, aug, q2, n, npad, xblocks, B);

  k_gemm<<<832, 256, 0, stream>>>(qb, xb, aug, cmin, C);

  k_tau<<<B, 256, 0, stream>>>(cmin, tau, kptr, ccnt, clist, C, B);
  k_exact<<<C, 256, 0, stream>>>(X, xt, aug, q2, tau, ccnt, clist, qcnt, cand, n, B);
  k_final<<<B, 64, 0, stream>>>(w, cand, qcnt, kptr, (float*)d_out, B, n);
}

// Round 6
// 226.077 us; speedup vs baseline: 1.9973x; 1.0246x over previous
//
#include <hip/hip_runtime.h>
#include <stdint.h>

typedef short   shortx8 __attribute__((ext_vector_type(8)));
typedef float   f32x4   __attribute__((ext_vector_type(4)));

#define CPS 8

static __device__ __forceinline__ unsigned short f2bf(float f) {
  unsigned u = __float_as_uint(f);
  unsigned r = u + 0x7FFFu + ((u >> 16) & 1u);   // RTNE
  return (unsigned short)(r >> 16);
}

static __device__ __forceinline__ void gl2lds16(const void* gsrc, void* ldst) {
  __builtin_amdgcn_global_load_lds(
      (const __attribute__((address_space(1))) unsigned int*)gsrc,
      (__attribute__((address_space(3))) unsigned int*)ldst, 16, 0, 0);
}

// ---- K1: fused {X->bf16, aug = ||x||^2 - w} and {xt->bf16, q2}; 16B/lane loads ----
__global__ void k_prep(const float* __restrict__ X, const float* __restrict__ xt,
                       const float* __restrict__ w, unsigned short* __restrict__ xb,
                       unsigned short* __restrict__ qb, float* __restrict__ aug,
                       float* __restrict__ q2, int n, int npad, int xblocks, int B) {
  const int hw = threadIdx.x >> 5;           // half-wave 0..7
  const int hl = threadIdx.x & 31;
  const int col = hl * 4;
  if ((int)blockIdx.x < xblocks) {
    int r = blockIdx.x * 8 + hw;
    if (r < n) {
      f32x4 v = *(const f32x4*)(X + (size_t)r * 128 + col);
      ushort4 us = make_ushort4(f2bf(v[0]), f2bf(v[1]), f2bf(v[2]), f2bf(v[3]));
      *(ushort4*)(xb + (size_t)r * 128 + col) = us;
      float s = v[0] * v[0] + v[1] * v[1] + v[2] * v[2] + v[3] * v[3];
      for (int m = 16; m; m >>= 1) s += __shfl_xor(s, m);
      if (hl == 0) aug[r] = s - w[r];
    } else {
      *(ushort4*)(xb + (size_t)r * 128 + col) = make_ushort4(0, 0, 0, 0);
      if (hl == 0) aug[r] = 1e30f;
    }
  } else {
    int r = (blockIdx.x - xblocks) * 8 + hw;
    f32x4 v = *(const f32x4*)(xt + (size_t)r * 128 + col);
    ushort4 us = make_ushort4(f2bf(v[0]), f2bf(v[1]), f2bf(v[2]), f2bf(v[3]));
    *(ushort4*)(qb + (size_t)r * 128 + col) = us;
    float s = v[0] * v[0] + v[1] * v[1] + v[2] * v[2] + v[3] * v[3];
    for (int m = 16; m; m >>= 1) s += __shfl_xor(s, m);
    if (hl == 0) q2[r] = s;
  }
}

// ---- K2: bf16 MFMA -> per-(query,chunk64) min of s' = aug - 2*dot ----
// T3/T4: 3-deep gl2lds pipeline, counted vmcnt(4) (never 0 mid-loop) + raw
// s_barrier; aug in LDS (keeps vmcnt stream pure); T5 setprio around MFMA.
__global__ __launch_bounds__(256, 3) void k_gemm(const unsigned short* __restrict__ qb,
    const unsigned short* __restrict__ xb, const float* __restrict__ aug,
    float* __restrict__ cmin, int C) {
  __shared__ __align__(16) unsigned short tile[3][8192];   // 3 x 16KB; reused as out-bounce
  __shared__ __align__(16) float augs[CPS * 64];           // stripe aug values
  const int S = C / CPS;                     // 196 stripes
  const int b = blockIdx.x;
  const int xcd = b & 7;
  const int j = b >> 3;                      // 0..199
  const int sj = j % 25, xq = j / 25;        // xq 0..7
  const int qq = S >> 3, rr = S & 7;         // bijective split: 24, 4
  const int nst = (xcd < rr) ? (qq + 1) : qq;
  if (sj >= nst) return;
  const int ystripe = (xcd < rr) ? (xcd * (qq + 1) + sj)
                                 : (rr * (qq + 1) + (xcd - rr) * qq + sj);
  const int c0 = ystripe * CPS;

  const int t = threadIdx.x;
  const int lane = t & 63, wv = t >> 6;
  const int li = lane & 15, lg = lane >> 4;
  const int qbase = xq * 256 + wv * 64;

  // B operand: 64 queries x K=128 resident in registers
  shortx8 qf[4][4];
#pragma unroll
  for (int qt = 0; qt < 4; ++qt)
#pragma unroll
    for (int ks = 0; ks < 4; ++ks)
      qf[qt][ks] = *(const shortx8*)(qb + (size_t)(qbase + qt * 16 + li) * 128 + ks * 32 + lg * 8);

  // stripe aug -> LDS (2 floats/thread)
  {
    float2 a2 = *(const float2*)(aug + (size_t)c0 * 64 + t * 2);
    *(float2*)&augs[t * 2] = a2;
  }

  // pre-swizzled global source offsets (linear LDS dest, swizzled ds_read)
  int soff[4];
#pragma unroll
  for (int jj = 0; jj < 4; ++jj) {
    int o = wv * 4096 + jj * 1024 + lane * 16;
    int r = o >> 8;
    soff[jj] = (o & ~255) | ((o & 255) ^ ((r & 7) << 4));
  }

#define STAGE(buf, cc) do {                                                  \
    const char* _s = (const char*)xb + (size_t)(cc) * 16384;                 \
    _Pragma("unroll")                                                        \
    for (int _j = 0; _j < 4; ++_j)                                           \
      gl2lds16(_s + soff[_j], &tile[buf][wv * 2048 + _j * 512]);             \
  } while (0)

  float cm[4][2];      // [qt][chunk>>2], owner lane: lg == chunk&3
#pragma unroll
  for (int qt = 0; qt < 4; ++qt)
#pragma unroll
    for (int jj = 0; jj < 2; ++jj) cm[qt][jj] = 1e38f;

  __syncthreads();                           // augs visible (also drains aug loads)
  STAGE(0, c0);
  STAGE(1, c0 + 1);

#pragma unroll
  for (int cc = 0; cc < CPS; ++cc) {
    const int cur = cc % 3;
    // wait oldest stage (chunk cc) landed; keep 1 stage in flight (T4: never 0 mid-loop)
    if (cc < CPS - 1) asm volatile("s_waitcnt vmcnt(4)" ::: "memory");
    else              asm volatile("s_waitcnt vmcnt(0)" ::: "memory");
    __builtin_amdgcn_s_barrier();            // raw: no compiler vmcnt(0) drain
    __builtin_amdgcn_sched_barrier(0);
    if (cc + 2 < CPS) STAGE((cc + 2) % 3, c0 + cc + 2);   // overwrites buf read at cc-1: safe after barrier

    f32x4 acc[4][4];
#pragma unroll
    for (int rg = 0; rg < 4; ++rg)
#pragma unroll
      for (int qt = 0; qt < 4; ++qt)
        acc[rg][qt] = (f32x4){0.f, 0.f, 0.f, 0.f};

    __builtin_amdgcn_s_setprio(1);
#pragma unroll
    for (int rg = 0; rg < 4; ++rg) {
      const int r = rg * 16 + li;
      const int rsw = (r & 7) << 3;
      shortx8 af[4];
#pragma unroll
      for (int ks = 0; ks < 4; ++ks)
        af[ks] = *(const shortx8*)(&tile[cur][r * 128 + ((ks * 32 + lg * 8) ^ rsw)]);
#pragma unroll
      for (int qt = 0; qt < 4; ++qt)
#pragma unroll
        for (int ks = 0; ks < 4; ++ks)
          acc[rg][qt] = __builtin_amdgcn_mfma_f32_16x16x32_bf16(af[ks], qf[qt][ks], acc[rg][qt], 0, 0, 0);
    }
    __builtin_amdgcn_s_setprio(0);

    float m[4];
#pragma unroll
    for (int qt = 0; qt < 4; ++qt) {
      float v = 1e38f;
#pragma unroll
      for (int rg = 0; rg < 4; ++rg) {
        f32x4 avv = *(const f32x4*)&augs[cc * 64 + rg * 16 + lg * 4];
#pragma unroll
        for (int p = 0; p < 4; ++p)
          v = fminf(v, fmaf(-2.f, acc[rg][qt][p], avv[p]));
      }
      v = fminf(v, __shfl_xor(v, 16));
      v = fminf(v, __shfl_xor(v, 32));
      m[qt] = v;
    }
#pragma unroll
    for (int qt = 0; qt < 4; ++qt)
      cm[qt][cc >> 2] = (lg == (cc & 3)) ? m[qt] : cm[qt][cc >> 2];
  }
#undef STAGE

  __syncthreads();                           // full drain before tile reuse as bounce
  // coalesced cmin write via LDS bounce (stride 12 floats: 16B-aligned reads)
  float* outf = (float*)tile;
#pragma unroll
  for (int qt = 0; qt < 4; ++qt)
#pragma unroll
    for (int jj = 0; jj < 2; ++jj)
      outf[(wv * 64 + qt * 16 + li) * 12 + jj * 4 + lg] = cm[qt][jj];
  __syncthreads();
#pragma unroll
  for (int p = 0; p < 2; ++p) {
    int flat = p * 1024 + t * 4;
    int ql = flat >> 3, cix = flat & 7;      // cix in {0,4}
    f32x4 v = *(const f32x4*)&outf[ql * 12 + cix];
    *(f32x4*)&cmin[(size_t)(xq * 256 + ql) * C + c0 + cix] = v;
  }
}

// ---- K3: tau = (k-th smallest chunk-min)+1.5, fused per-chunk list append ----
__global__ void k_tau(const float* __restrict__ cmin, float* __restrict__ tau,
                      const int* __restrict__ kptr, int* __restrict__ ccnt,
                      int* __restrict__ clist, int C, int B) {
  __shared__ float arr[1600];
  __shared__ float red[4];
  __shared__ int   redi[4];
  __shared__ float bval;
  __shared__ int   bidx;
  const int q = blockIdx.x, t = threadIdx.x;
  const int lane = t & 63, wv = t >> 6;
  const float* row = cmin + (size_t)q * C;
  float lmd = 1e38f; int lmi = -1;
  for (int i = t; i < C; i += 256) {
    float v = row[i]; arr[i] = v;
    if (v < lmd) { lmd = v; lmi = i; }
  }
  __syncthreads();
  int k = *kptr; if (k < 1) k = 1; if (k > 32) k = 32;
  float tv = 1e38f;
  for (int r = 0; r < k; ++r) {
    float md = lmd; int mi = lmi;
    for (int msk = 32; msk; msk >>= 1) {
      float od = __shfl_xor(md, msk); int oi = __shfl_xor(mi, msk);
      if (od < md) { md = od; mi = oi; }
    }
    if (lane == 0) { red[wv] = md; redi[wv] = mi; }
    __syncthreads();
    if (t == 0) {
      float bm = red[0]; int bi = redi[0];
      for (int u = 1; u < 4; ++u) if (red[u] < bm) { bm = red[u]; bi = redi[u]; }
      bval = bm; bidx = bi;
    }
    __syncthreads();
    tv = bval;
    const int sel = bidx;
    if (r + 1 < k && sel >= 0 && (sel & 255) == t) {
      arr[sel] = 1e38f;
      lmd = 1e38f; lmi = -1;
      for (int i = t; i < C; i += 256) {
        float v = arr[i];
        if (v < lmd) { lmd = v; lmi = i; }
      }
    }
    __syncthreads();
  }
  const float tq = tv + 1.5f;
  if (t == 0) tau[q] = tq;
  for (int i = t; i < C; i += 256)
    if (row[i] <= tq) {
      int pos = atomicAdd(&ccnt[i], 1);
      clist[(size_t)i * B + pos] = q;
    }
}

// ---- K4: exact fp32 recompute; per-wave independent rounds of 4 queries ----
__global__ __launch_bounds__(256) void k_exact(const float* __restrict__ X, const float* __restrict__ xt,
    const float* __restrict__ aug, const float* __restrict__ q2, const float* __restrict__ tau,
    const int* __restrict__ ccnt, const int* __restrict__ clist,
    int* __restrict__ qcnt, float2* __restrict__ cand, int n, int B) {
  const int c = blockIdx.x;
  const int nq = ccnt[c];
  if (nq == 0) return;
  __shared__ float xs[64 * 128];     // swizzled quads
  __shared__ float qs[4 * 512];      // 4 waves x 4 queries x 128
  const int t = threadIdx.x, lane = t & 63, wv = t >> 6;
#pragma unroll
  for (int p = 0; p < 8; ++p) {
    int flat = p * 1024 + t * 4;
    int r = flat >> 7, col = flat & 127;
    long g = (long)c * 64 + r;
    f32x4 v = (f32x4){0.f, 0.f, 0.f, 0.f};
    if (g < n) v = *(const f32x4*)(X + g * 128 + col);
    *(f32x4*)&xs[r * 128 + ((((col >> 2) ^ (r & 31))) << 2)] = v;
  }
  const int gcol = c * 64 + lane;
  const float augv = aug[gcol];
  __syncthreads();

  float* qsw = qs + wv * 512;
  const int sw = lane & 31;
  const int su = (lane >> 4) & 3;           // staging: which query this lane loads
  const int scol = (lane & 15) * 8;
  for (int i0 = wv * 4; i0 < nq; i0 += 16) {
    const size_t cb = (size_t)c * B;
    int qn0 = __builtin_amdgcn_readfirstlane(clist[cb + min(i0 + 0, nq - 1)]);
    int qn1 = __builtin_amdgcn_readfirstlane(clist[cb + min(i0 + 1, nq - 1)]);
    int qn2 = __builtin_amdgcn_readfirstlane(clist[cb + min(i0 + 2, nq - 1)]);
    int qn3 = __builtin_amdgcn_readfirstlane(clist[cb + min(i0 + 3, nq - 1)]);
    {  // stage this wave's 4 queries (8 floats/lane)
      int qnu = (su == 0) ? qn0 : (su == 1) ? qn1 : (su == 2) ? qn2 : qn3;
      const float* Q = xt + (size_t)qnu * 128 + scol;
      *(f32x4*)&qsw[su * 128 + scol]     = *(const f32x4*)(Q);
      *(f32x4*)&qsw[su * 128 + scol + 4] = *(const f32x4*)(Q + 4);
    }
    float t0 = tau[qn0], t1 = tau[qn1], t2 = tau[qn2], t3 = tau[qn3];
    float g0 = q2[qn0], g1 = q2[qn1], g2 = q2[qn2], g3 = q2[qn3];
    float a0 = 0.f, a1 = 0.f, a2 = 0.f, a3 = 0.f;
#pragma unroll 4
    for (int jj = 0; jj < 32; ++jj) {
      f32x4 xv = *(const f32x4*)&xs[lane * 128 + ((jj ^ sw) << 2)];
      f32x4 v0 = *(const f32x4*)&qsw[0 * 128 + jj * 4];
      f32x4 v1 = *(const f32x4*)&qsw[1 * 128 + jj * 4];
      f32x4 v2 = *(const f32x4*)&qsw[2 * 128 + jj * 4];
      f32x4 v3 = *(const f32x4*)&qsw[3 * 128 + jj * 4];
#pragma unroll
      for (int e = 0; e < 4; ++e) {
        a0 = fmaf(xv[e], v0[e], a0);
        a1 = fmaf(xv[e], v1[e], a1);
        a2 = fmaf(xv[e], v2[e], a2);
        a3 = fmaf(xv[e], v3[e], a3);
      }
    }
#pragma unroll
    for (int u = 0; u < 4; ++u) {
      const float accv = (u == 0) ? a0 : (u == 1) ? a1 : (u == 2) ? a2 : a3;
      const int qnu   = (u == 0) ? qn0 : (u == 1) ? qn1 : (u == 2) ? qn2 : qn3;
      const float tuu = (u == 0) ? t0 : (u == 1) ? t1 : (u == 2) ? t2 : t3;
      const float g2u = (u == 0) ? g0 : (u == 1) ? g1 : (u == 2) ? g2 : g3;
      const float s = fmaf(-2.f, accv, augv);
      if ((i0 + u) < nq && gcol < n && s <= tuu) {
        int pos = atomicAdd(&qcnt[qnu], 1);
        if (pos < 256) {
          float d2v = fmaf(-2.f, accv, g2u) + augv;
          cand[(size_t)qnu * 256 + pos] = make_float2(d2v, __int_as_float(gcol));
        }
      }
    }
  }
}

// ---- K5: exact top-k (ascending (d2',idx)) + argmax f; f = w - sqrt(relu(d2'+w)) ----
__global__ void k_final(const float* __restrict__ w,
    const float2* __restrict__ cand, const int* __restrict__ qcnt, const int* __restrict__ kptr,
    float* __restrict__ dout, int B, int n) {
  const int q = blockIdx.x, lane = threadIdx.x;
  int k = *kptr; if (k < 1) k = 1; if (k > 64) k = 64;
  const int cnt = min(qcnt[q], 256);
  float d0 = 1e38f, d1 = 1e38f, d2v = 1e38f, d3 = 1e38f;
  int i0 = 0x7fffffff, i1 = 0x7fffffff, i2 = 0x7fffffff, i3 = 0x7fffffff;
  {
    int s;
    s = lane;       if (s < cnt) { float2 cc = cand[(size_t)q * 256 + s]; d0 = cc.x; i0 = __float_as_int(cc.y); }
    s = lane + 64;  if (s < cnt) { float2 cc = cand[(size_t)q * 256 + s]; d1 = cc.x; i1 = __float_as_int(cc.y); }
    s = lane + 128; if (s < cnt) { float2 cc = cand[(size_t)q * 256 + s]; d2v = cc.x; i2 = __float_as_int(cc.y); }
    s = lane + 192; if (s < cnt) { float2 cc = cand[(size_t)q * 256 + s]; d3 = cc.x; i3 = __float_as_int(cc.y); }
  }
  float bestf = -1e38f; int besti = 0;
  for (int r = 0; r < k; ++r) {
    float md = d0; int mi = i0; int mj = 0;
    if (d1 < md || (d1 == md && i1 < mi)) { md = d1; mi = i1; mj = 1; }
    if (d2v < md || (d2v == md && i2 < mi)) { md = d2v; mi = i2; mj = 2; }
    if (d3 < md || (d3 == md && i3 < mi)) { md = d3; mi = i3; mj = 3; }
    int ml = lane;
    for (int msk = 32; msk; msk >>= 1) {
      float od = __shfl_xor(md, msk); int oi = __shfl_xor(mi, msk);
      int ol = __shfl_xor(ml, msk);   int oj = __shfl_xor(mj, msk);
      if (od < md || (od == md && oi < mi)) { md = od; mi = oi; ml = ol; mj = oj; }
    }
    if (lane == ml) {
      if (mj == 0)      { d0 = 1e38f;  i0 = 0x7fffffff; }
      else if (mj == 1) { d1 = 1e38f;  i1 = 0x7fffffff; }
      else if (mj == 2) { d2v = 1e38f; i2 = 0x7fffffff; }
      else              { d3 = 1e38f;  i3 = 0x7fffffff; }
    }
    if (mi >= 0 && mi < n) {
      float wi = w[mi];
      float da = sqrtf(fmaxf(md + wi, 0.f));
      float f = wi - da;
      if (f > bestf) { bestf = f; besti = mi; }
    }
  }
  if (lane == 0) { dout[q] = bestf; dout[B + q] = (float)besti; }
}

extern "C" void kernel_launch(void* const* d_in, const int* in_sizes, int n_in,
                              void* d_out, int out_size, void* d_ws, size_t ws_size,
                              hipStream_t stream) {
  const float* xt = (const float*)d_in[0];
  const float* X  = (const float*)d_in[1];
  const float* w  = (const float*)d_in[2];
  const int* kptr = (const int*)d_in[3];
  const int B = in_sizes[0] / 128;            // 2048
  const int n = in_sizes[2];                  // 100000
  const int C = ((n + 63) / 64 + CPS - 1) / CPS * CPS;  // 1568 (stripe multiple)
  const int npad = C * 64;                    // 100352

  char* ws = (char*)d_ws;
  const size_t o_ccnt = 0;                                   // C ints (<= 8192 B)
  const size_t o_qcnt = 8192;                                // B ints
  const size_t o_q2   = 16384;
  const size_t o_tau  = o_q2 + (size_t)B * 4;
  const size_t o_aug  = o_tau + (size_t)B * 4;
  const size_t o_cmin = (o_aug + (size_t)npad * 4 + 255) & ~(size_t)255;
  const size_t o_clist= (o_cmin + (size_t)B * C * 4 + 255) & ~(size_t)255;
  const size_t o_cand = (o_clist + (size_t)C * B * 4 + 255) & ~(size_t)255;
  const size_t o_qb   = (o_cand + (size_t)B * 256 * 8 + 255) & ~(size_t)255;
  const size_t o_xb   = (o_qb + (size_t)B * 128 * 2 + 255) & ~(size_t)255;

  int* ccnt  = (int*)(ws + o_ccnt);
  int* qcnt  = (int*)(ws + o_qcnt);
  float* q2  = (float*)(ws + o_q2);
  float* tau = (float*)(ws + o_tau);
  float* aug = (float*)(ws + o_aug);
  float* cmin = (float*)(ws + o_cmin);
  int* clist = (int*)(ws + o_clist);
  float2* cand = (float2*)(ws + o_cand);
  unsigned short* qb = (unsigned short*)(ws + o_qb);
  unsigned short* xb = (unsigned short*)(ws + o_xb);

  hipMemsetAsync(d_ws, 0, 16384, stream);     // ccnt + qcnt

  const int xblocks = npad / 8;               // 12544
  k_prep<<<xblocks + B / 8, 256, 0, stream>>>(X, xt, w, xb, qb, aug, q2, n, npad, xblocks, B);

  k_gemm<<<1600, 256, 0, stream>>>(qb, xb, aug, cmin, C);   // 8 xcd x 25 sj x 8 xq

  k_tau<<<B, 256, 0, stream>>>(cmin, tau, kptr, ccnt, clist, C, B);
  k_exact<<<C, 256, 0, stream>>>(X, xt, aug, q2, tau, ccnt, clist, qcnt, cand, n, B);
  k_final<<<B, 64, 0, stream>>>(w, cand, qcnt, kptr, (float*)d_out, B, n);
}